// Round 7
// baseline (1387.745 us; speedup 1.0000x reference)
//
#include <hip/hip_runtime.h>
#include <hip/hip_fp16.h>
#include <math.h>

#define HN 512   // hidden states
#define HM 4096  // emission symbols
#define HB 64    // batch
#define HT 512   // max seq len

using h2v = decltype(__builtin_amdgcn_cvt_pkrtz(0.f, 0.f));  // __fp16 ext_vector(2)

__device__ __forceinline__ h2v uh2(unsigned int u){ union{unsigned int u; h2v v;} c; c.u=u; return c.v; }
__device__ __forceinline__ h2v pkh2(float a, float b){ return __builtin_amdgcn_cvt_pkrtz(a, b); }
__device__ __forceinline__ unsigned short f16bits(float a){
  union{ h2v v; unsigned int u; } c; c.v = __builtin_amdgcn_cvt_pkrtz(a, a);
  return (unsigned short)(c.u & 0xffffu);
}

__device__ __forceinline__ float dot2(h2v a, h2v b, float c){
#if __has_builtin(__builtin_amdgcn_fdot2)
  return __builtin_amdgcn_fdot2(a, b, c, false);
#else
  return c + (float)a[0]*(float)b[0] + (float)a[1]*(float)b[1];
#endif
}

__device__ __forceinline__ float wsum(float v){
  #pragma unroll
  for(int o=32;o>0;o>>=1) v += __shfl_xor(v,o,64);
  return v;
}
__device__ __forceinline__ float wmax(float v){
  #pragma unroll
  for(int o=32;o>0;o>>=1) v = fmaxf(v,__shfl_xor(v,o,64));
  return v;
}

__device__ __forceinline__ float blockSum512(float v, float* red, float* bc){
  v = wsum(v);
  if((threadIdx.x & 63)==0) red[threadIdx.x>>6] = v;
  __syncthreads();
  if(threadIdx.x < 64){
    float s = (threadIdx.x<8)? red[threadIdx.x] : 0.0f;
    #pragma unroll
    for(int o=4;o>0;o>>=1) s += __shfl_xor(s,o,64);
    if(threadIdx.x==0) *bc = s;
  }
  __syncthreads();
  return *bc;
}
__device__ __forceinline__ float blockMax512(float v, float* red, float* bc){
  v = wmax(v);
  if((threadIdx.x & 63)==0) red[threadIdx.x>>6] = v;
  __syncthreads();
  if(threadIdx.x < 64){
    float s = (threadIdx.x<8)? red[threadIdx.x] : -INFINITY;
    #pragma unroll
    for(int o=4;o>0;o>>=1) s = fmaxf(s, __shfl_xor(s,o,64));
    if(threadIdx.x==0) *bc = s;
  }
  __syncthreads();
  return *bc;
}

__device__ __forceinline__ unsigned short f2bf(float f){
  unsigned int u = __float_as_uint(f);
  unsigned int r = (u + 0x7fffu + ((u>>16)&1u)) >> 16;  // RNE
  return (unsigned short)r;
}
__device__ __forceinline__ float bf2f(unsigned int w){ return __uint_as_float(w<<16); }

__device__ __forceinline__ float f8dec(unsigned int b){
  unsigned e = (b>>3)&15u, m = b&7u;
  float v = e ? ldexpf(8.0f + (float)m, (int)e - 10) : ldexpf((float)m, -9);
  return (b & 0x80u) ? -v : v;
}
template<bool HI>
__device__ __forceinline__ void f8pair(unsigned int dw, float& a, float& b){
#if __has_builtin(__builtin_amdgcn_cvt_pk_f32_fp8)
  auto r = __builtin_amdgcn_cvt_pk_f32_fp8((int)dw, HI);
  a = r[0]; b = r[1];
#else
  unsigned int s = HI ? (dw>>16) : dw;
  a = f8dec(s & 0xffu); b = f8dec((s>>8)&0xffu);
#endif
}
__device__ __forceinline__ unsigned char f8enc(float v){
#if __has_builtin(__builtin_amdgcn_cvt_pk_fp8_f32)
  int p = __builtin_amdgcn_cvt_pk_fp8_f32(v, v, 0, false);
  return (unsigned char)(p & 0xff);
#else
  if(!(v > 0.0f)) return 0;
  if(v >= 448.0f) return 0x7e;
  int e; frexpf(v, &e);
  int E = e + 6;
  if(E <= 0){
    float q = rintf(ldexpf(v, 9));
    return (unsigned char)q;
  }
  float q = rintf(ldexpf(v, 4 - e));
  if(q >= 16.0f){ E++; q = 8.0f; }
  if(E > 15) return 0x7e;
  return (unsigned char)((E<<3) | ((int)q - 8));
#endif
}

// ---------------- prep kernels ----------------

__global__ __launch_bounds__(512) void k_em_lse(const float* __restrict__ em, float* __restrict__ em_lse){
  __shared__ float red[8]; __shared__ float bc;
  int r = blockIdx.x;
  const float* row = em + (size_t)r*HM;
  float mx = -INFINITY;
  for(int i=threadIdx.x;i<HM;i+=512) mx = fmaxf(mx, row[i]);
  mx = blockMax512(mx, red, &bc);
  float s = 0.f;
  for(int i=threadIdx.x;i<HM;i+=512) s += expf(row[i]-mx);
  s = blockSum512(s, red, &bc);
  if(threadIdx.x==0) em_lse[r] = mx + logf(s);
}

__global__ __launch_bounds__(512) void k_pri(const float* __restrict__ pri, float* __restrict__ P, float* __restrict__ pric){
  __shared__ float red[8]; __shared__ float bc;
  int j = threadIdx.x;
  float v = pri[j];
  float mx = blockMax512(v, red, &bc);
  float w = expf(v-mx);
  float s = blockSum512(w, red, &bc);
  P[j] = w;
  if(j==0) *pric = -logf(s);
}

// emT[m][j] = bf16( exp(log_em[j][m]) ), LDS-tiled transpose
__global__ __launch_bounds__(256) void k_em_tab(const float* __restrict__ em, const float* __restrict__ em_lse,
                                                unsigned short* __restrict__ emT){
  __shared__ unsigned short tile[64][66];
  __shared__ float lsl[64];
  int m0 = blockIdx.x*64, j0 = blockIdx.y*64;
  int tx = threadIdx.x & 63, ty = threadIdx.x >> 6;
  if(threadIdx.x < 64) lsl[threadIdx.x] = em_lse[j0 + threadIdx.x];
  __syncthreads();
  #pragma unroll
  for(int r=0;r<16;r++){
    int jl = ty*16 + r;
    float v = em[(size_t)(j0+jl)*HM + m0 + tx];
    tile[jl][tx] = f2bf(expf(v - lsl[jl]));
  }
  __syncthreads();
  #pragma unroll
  for(int r=0;r<16;r++){
    int ml = ty*16 + r;
    emT[(size_t)(m0+ml)*HN + j0 + tx] = tile[tx][ml];
  }
}

// col-softmax of transition, scaled x256, ALL fp8 e4m3.
// rows j%8<4 -> G8 (register-staged table), j%8>=4 -> L8 (LDS table).
__global__ __launch_bounds__(512) void k_tr(const float* __restrict__ tr,
                                            unsigned char* __restrict__ G8,
                                            unsigned char* __restrict__ L8){
  __shared__ float red[8]; __shared__ float bc;
  int k = blockIdx.x, j = threadIdx.x;
  float v = tr[(size_t)j*HN + k];
  float mx = blockMax512(v, red, &bc);
  float wv = expf(v-mx);
  float s = blockSum512(wv, red, &bc);
  float p = 256.0f * (wv / s);
  int w = k>>6, kl = k&63, l = j>>3, i = j&7;
  unsigned char enc = f8enc(p);
  if(i < 4){
    // register part: dword r = i*16 + h*8 + q (h=k-half, q=k-quad), byte d
    int h = (kl>>5)&1, q = (kl>>2)&7, d = kl&3, r = i*16 + h*8 + q;
    G8[(((size_t)(w*64 + r)*64 + l)<<2) + d] = enc;
  } else {
    L8[((size_t)((w*16) + (i-4)*4 + (kl>>4))*64 + l)*16 + (kl&15)] = enc;
  }
}

// ---------------- forward recurrence ----------------
// 64 blocks (1/batch), 512 threads. wave w owns k in [64w,64w+64); lane l owns
// outputs j in {8l+i}. i<4 from fp8 register Tr (trr8[64] dwords), i>=4 from
// fp8 LDS Tr. K processed in two 32-state halves to cut live pressure:
// live ~ 64(trr8)+16(apk)+8(acc)+~30 = ~120 <= the allocator's observed 128-VGPR
// budget (rounds 3-6: f16 trr[128] needed ~190 -> spilled/refetched 256KB/CU/step
// from L2; VGPR stuck at 116, dur frozen at ~1.3ms).
__global__ __launch_bounds__(512) __attribute__((amdgpu_waves_per_eu(1, 2)))
void k_fwd(const int* __restrict__ x, const int* __restrict__ Tl,
           const unsigned short* __restrict__ emTu,
           const float* __restrict__ P, const float* __restrict__ pric,
           const unsigned int* __restrict__ G8u,
           const uint4* __restrict__ Lfp8,
           float* __restrict__ out){
  extern __shared__ char smem[];
  // ah 1024 | red2 64 | xls 2048 | red 16384 | trl 131072  = 150592 B
  uint4*  ah4  = (uint4*)smem;
  unsigned short* ah16 = (unsigned short*)smem;
  float*  red2 = (float*)(smem + 1024);
  int*    xls  = (int*)(smem + 1088);
  float*  red  = (float*)(smem + 3136);
  uint4*  trl  = (uint4*)(smem + 19520);

  const int t = threadIdx.x, w = t>>6, l = t&63, b = blockIdx.x;

  xls[t] = x[b*HT + t];
  for(int i=t;i<8192;i+=512) trl[i] = Lfp8[i];

  unsigned int trr8[64];
  #pragma unroll
  for(int r=0;r<64;r++) trr8[r] = G8u[(w*64 + r)*64 + l];
  #pragma unroll
  for(int r=0;r<64;r++) asm volatile("" : "+v"(trr8[r]));

  int Tb = Tl[b];
  __syncthreads();

  // ---- t = 0 ----
  int   m  = xls[0];
  float e  = bf2f((unsigned)emTu[(size_t)m*HN + t]);
  float nu = e * P[t];
  {
    float vs = wsum(nu);
    if(l==0) red2[w] = vs;
  }
  __syncthreads();
  float4 r0 = ((float4*)red2)[0], r1 = ((float4*)red2)[1];
  float S = ((r0.x+r0.y)+(r0.z+r0.w))+((r1.x+r1.y)+(r1.z+r1.w));
  float c = pric[0] + __logf(S);
  float sc = 256.0f / S;
  ah16[t] = f16bits(nu * sc);     // wave-local: wave w's slice written by wave w
  int   mn = xls[(Tb>1)?1:0];
  float en = bf2f((unsigned)emTu[(size_t)mn*HN + t]);

  for(int tt=1; tt<Tb; tt++){
    e = en;
    int tnx = (tt+1 < HT)? tt+1 : HT-1;
    mn = xls[tnx];
    en = bf2f((unsigned)emTu[(size_t)mn*HN + t]);    // prefetch next step

    // ---- Phase A: partials over this wave's k-range, two 32-state halves ----
    float acc[8];
    #pragma unroll
    for(int i=0;i<8;i++) acc[i] = 0.0f;

    #pragma unroll
    for(int h=0;h<2;h++){
      unsigned int apk[16];
      {
        uint4* ap4 = (uint4*)apk;
        #pragma unroll
        for(int q=0;q<4;q++) ap4[q] = ah4[8*w + 4*h + q];
      }
      // register rows i<4
      #pragma unroll
      for(int i=0;i<4;i++){
        #pragma unroll
        for(int q=0;q<8;q++){
          unsigned int dw = trr8[i*16 + h*8 + q];
          float fa, fb;
          f8pair<false>(dw, fa, fb);
          acc[i] = dot2(pkh2(fa,fb), uh2(apk[2*q]), acc[i]);
          f8pair<true>(dw, fa, fb);
          acc[i] = dot2(pkh2(fa,fb), uh2(apk[2*q+1]), acc[i]);
        }
      }
      // LDS rows i>=4: quads qq = 2h, 2h+1 belong to half h
      #pragma unroll
      for(int i5=0;i5<4;i5++){
        #pragma unroll
        for(int qh=0;qh<2;qh++){
          int qq = 2*h + qh;
          uint4 F = trl[(w*16 + i5*4 + qq)*64 + l];
          unsigned int dws[4] = {F.x, F.y, F.z, F.w};
          #pragma unroll
          for(int d=0; d<4; d++){
            int pl = 8*qh + 2*d;   // local pair index in this half
            float fa, fb;
            f8pair<false>(dws[d], fa, fb);
            acc[4+i5] = dot2(pkh2(fa,fb), uh2(apk[pl]), acc[4+i5]);
            f8pair<true>(dws[d], fa, fb);
            acc[4+i5] = dot2(pkh2(fa,fb), uh2(apk[pl+1]), acc[4+i5]);
          }
        }
      }
    }
    // swizzled partial store: output j=8l+i from wave w at red[i*512 + w*64 + (l^(8i))]
    #pragma unroll
    for(int i=0;i<8;i++) red[i*512 + w*64 + (l ^ (i<<3))] = acc[i];
    __syncthreads();                       // B1

    // ---- Phase B: thread t finalizes output j = t ----
    {
      int lo = t>>3, ii = t&7;
      float v = 0.f;
      #pragma unroll
      for(int ww=0;ww<8;ww++) v += red[ii*512 + ww*64 + (lo ^ (ii<<3))];
      v *= (1.0f/65536.0f);
      nu = v * e;
    }
    {
      float vs = wsum(nu);
      if(l==0) red2[w] = vs;
    }
    __syncthreads();                       // B2
    float4 q0 = ((float4*)red2)[0], q1 = ((float4*)red2)[1];
    S = ((q0.x+q0.y)+(q0.z+q0.w))+((q1.x+q1.y)+(q1.z+q1.w));
    c += __logf(S);
    sc = 256.0f / S;
    ah16[t] = f16bits(nu * sc);            // own-wave consumption next iter; B2-protected vs red
  }
  if(t==0) out[b] = c;
}

extern "C" void kernel_launch(void* const* d_in, const int* in_sizes, int n_in,
                              void* d_out, int out_size, void* d_ws, size_t ws_size,
                              hipStream_t stream){
  const int*   x   = (const int*)d_in[0];
  const int*   T   = (const int*)d_in[1];
  const float* em  = (const float*)d_in[2];
  const float* tr  = (const float*)d_in[3];
  const float* pri = (const float*)d_in[4];
  float* out = (float*)d_out;

  char* ws = (char*)d_ws;
  float* em_lse = (float*)ws;                                   // 2 KiB
  float* P      = (float*)(ws + 2048);                          // 2 KiB
  float* pric   = (float*)(ws + 4096);                          // 16 B
  unsigned short* emT = (unsigned short*)(ws + 24576);          // 4 MiB
  unsigned char*  G8  = (unsigned char*)(ws + 24576 + (size_t)HM*HN*2);            // 128 KiB
  unsigned char*  L8  = (unsigned char*)(ws + 24576 + (size_t)HM*HN*2 + 131072);   // 128 KiB

  k_em_lse<<<HN, 512, 0, stream>>>(em, em_lse);
  k_pri  <<<1,  512, 0, stream>>>(pri, P, pric);
  k_tr   <<<HN, 512, 0, stream>>>(tr, G8, L8);
  k_em_tab<<<dim3(HM/64, HN/64), 256, 0, stream>>>(em, em_lse, emT);

  const int lds_bytes = 19520 + 131072;   // 150592
  (void)hipFuncSetAttribute((const void*)k_fwd, hipFuncAttributeMaxDynamicSharedMemorySize, lds_bytes);
  k_fwd  <<<HB, 512, lds_bytes, stream>>>(x, T, emT, P, pric,
                                          (const unsigned int*)G8, (const uint4*)L8, out);
}

// Round 8
// 1071.543 us; speedup vs baseline: 1.2951x; 1.2951x over previous
//
#include <hip/hip_runtime.h>
#include <math.h>

#define HN 512   // hidden states
#define HM 4096  // emission symbols
#define HB 64    // batch
#define HT 512   // max seq len

__device__ __forceinline__ int dot4u8(unsigned int a, unsigned int b, int c){
#if __has_builtin(__builtin_amdgcn_sdot4)
  return __builtin_amdgcn_sdot4((int)a, (int)b, c, false);   // bytes <=127 -> sign-safe
#elif __has_builtin(__builtin_amdgcn_udot4)
  return (int)__builtin_amdgcn_udot4(a, b, (unsigned)c, false);
#else
  c += (int)(a & 0xffu)        * (int)(b & 0xffu);
  c += (int)((a>>8) & 0xffu)   * (int)((b>>8) & 0xffu);
  c += (int)((a>>16) & 0xffu)  * (int)((b>>16) & 0xffu);
  c += (int)(a>>24)            * (int)(b>>24);
  return c;
#endif
}

__device__ __forceinline__ float wsum(float v){
  #pragma unroll
  for(int o=32;o>0;o>>=1) v += __shfl_xor(v,o,64);
  return v;
}
__device__ __forceinline__ float wmax(float v){
  #pragma unroll
  for(int o=32;o>0;o>>=1) v = fmaxf(v,__shfl_xor(v,o,64));
  return v;
}

__device__ __forceinline__ float blockSum512(float v, float* red, float* bc){
  v = wsum(v);
  if((threadIdx.x & 63)==0) red[threadIdx.x>>6] = v;
  __syncthreads();
  if(threadIdx.x < 64){
    float s = (threadIdx.x<8)? red[threadIdx.x] : 0.0f;
    #pragma unroll
    for(int o=4;o>0;o>>=1) s += __shfl_xor(s,o,64);
    if(threadIdx.x==0) *bc = s;
  }
  __syncthreads();
  return *bc;
}
__device__ __forceinline__ float blockMax512(float v, float* red, float* bc){
  v = wmax(v);
  if((threadIdx.x & 63)==0) red[threadIdx.x>>6] = v;
  __syncthreads();
  if(threadIdx.x < 64){
    float s = (threadIdx.x<8)? red[threadIdx.x] : -INFINITY;
    #pragma unroll
    for(int o=4;o>0;o>>=1) s = fmaxf(s, __shfl_xor(s,o,64));
    if(threadIdx.x==0) *bc = s;
  }
  __syncthreads();
  return *bc;
}

__device__ __forceinline__ unsigned short f2bf(float f){
  unsigned int u = __float_as_uint(f);
  unsigned int r = (u + 0x7fffu + ((u>>16)&1u)) >> 16;  // RNE
  return (unsigned short)r;
}
__device__ __forceinline__ float bf2f(unsigned int w){ return __uint_as_float(w<<16); }

// ---------------- prep kernels ----------------

__global__ __launch_bounds__(512) void k_em_lse(const float* __restrict__ em, float* __restrict__ em_lse){
  __shared__ float red[8]; __shared__ float bc;
  int r = blockIdx.x;
  const float* row = em + (size_t)r*HM;
  float mx = -INFINITY;
  for(int i=threadIdx.x;i<HM;i+=512) mx = fmaxf(mx, row[i]);
  mx = blockMax512(mx, red, &bc);
  float s = 0.f;
  for(int i=threadIdx.x;i<HM;i+=512) s += expf(row[i]-mx);
  s = blockSum512(s, red, &bc);
  if(threadIdx.x==0) em_lse[r] = mx + logf(s);
}

__global__ __launch_bounds__(512) void k_pri(const float* __restrict__ pri, float* __restrict__ P, float* __restrict__ pric){
  __shared__ float red[8]; __shared__ float bc;
  int j = threadIdx.x;
  float v = pri[j];
  float mx = blockMax512(v, red, &bc);
  float w = expf(v-mx);
  float s = blockSum512(w, red, &bc);
  P[j] = w;
  if(j==0) *pric = -logf(s);
}

// emT[m][j] = bf16( exp(log_em[j][m]) ), LDS-tiled transpose
__global__ __launch_bounds__(256) void k_em_tab(const float* __restrict__ em, const float* __restrict__ em_lse,
                                                unsigned short* __restrict__ emT){
  __shared__ unsigned short tile[64][66];
  __shared__ float lsl[64];
  int m0 = blockIdx.x*64, j0 = blockIdx.y*64;
  int tx = threadIdx.x & 63, ty = threadIdx.x >> 6;
  if(threadIdx.x < 64) lsl[threadIdx.x] = em_lse[j0 + threadIdx.x];
  __syncthreads();
  #pragma unroll
  for(int r=0;r<16;r++){
    int jl = ty*16 + r;
    float v = em[(size_t)(j0+jl)*HM + m0 + tx];
    tile[jl][tx] = f2bf(expf(v - lsl[jl]));
  }
  __syncthreads();
  #pragma unroll
  for(int r=0;r<16;r++){
    int ml = ty*16 + r;
    emT[(size_t)(m0+ml)*HN + j0 + tx] = tile[tx][ml];
  }
}

// column stats of transition col-softmax: cmax[k], csum[k]
__global__ __launch_bounds__(512) void k_trcol(const float* __restrict__ tr,
                                               float* __restrict__ cmax, float* __restrict__ csum){
  __shared__ float red[8]; __shared__ float bc;
  int k = blockIdx.x, j = threadIdx.x;
  float v = tr[(size_t)j*HN + k];
  float mx = blockMax512(v, red, &bc);
  float s  = blockSum512(expf(v-mx), red, &bc);
  if(j==0){ cmax[k] = mx; csum[k] = s; }
}

// row pass: Tr[j,k] = exp(tr-cmax)/csum; rm_j = row max; TQb[j][k] = u8 round(Tr*127/rm);
// rscale[j] = rm_j/127 (descale folded)
__global__ __launch_bounds__(512) void k_trrow(const float* __restrict__ tr,
                                               const float* __restrict__ cmax, const float* __restrict__ csum,
                                               unsigned char* __restrict__ TQb, float* __restrict__ rscale){
  __shared__ float red[8]; __shared__ float bc;
  int j = blockIdx.x, k = threadIdx.x;
  float v = expf(tr[(size_t)j*HN + k] - cmax[k]) / csum[k];
  float rm = blockMax512(v, red, &bc);
  TQb[(size_t)j*HN + k] = (unsigned char)__float2int_rn(v * (127.0f/rm));
  if(k==0) rscale[j] = rm * (1.0f/127.0f);
}

// ---------------- forward recurrence ----------------
// 64 blocks (1/batch), 1024 threads = 16 waves (4/SIMD: good latency hiding).
// wave w: k-slice kr=w>>1, j-half jh=w&1. Thread (w,L): 4 output j = jh*256+4L+i,
// Tr slice 4jx64k as u8 in trq[64] REGISTERS (u8 dot4: no decode, no LDS Tr).
// alpha: u8, wave-local registers apk[16]; repacked per step via wave-private LDS
// (no barrier). 2 barriers/step. Scaled-linear recurrence with deferred scales:
// c += log(S_raw) - log120 + log r_prev;  aq = round(nv*120/M).
__global__ __launch_bounds__(1024)
void k_fwd(const int* __restrict__ x, const int* __restrict__ Tl,
           const unsigned short* __restrict__ emTu,
           const float* __restrict__ P, const float* __restrict__ pric,
           const float* __restrict__ rscale,
           const unsigned char* __restrict__ TQb,
           float* __restrict__ out){
  __shared__ int   xls[HT];
  __shared__ int   redi[4096];                 // partials: ((w)*4+i)*64 + l
  __shared__ float red2[16];                   // [kr]=sum, [8+kr]=max
  __shared__ __align__(16) unsigned char aqb[1024];  // wave-private alpha u8: w*64+L

  const int t = threadIdx.x, w = t>>6, L = t&63, b = blockIdx.x;
  const int kr = w>>1, jh = w&1;
  const int jstar = kr*64 + L;                 // the state this thread finalizes
  const int ii = jstar & 3, jh2 = jstar >> 8, ll = (jstar >> 2) & 63;

  if(t < HT) xls[t] = x[b*HT + t];

  // stage register Tr tile: 4 rows x 64 k-bytes = 16 uint4
  unsigned int trq[64];
  #pragma unroll
  for(int i=0;i<4;i++){
    int j = jh*256 + 4*L + i;
    const uint4* src = (const uint4*)(TQb + (size_t)j*HN + kr*64);
    #pragma unroll
    for(int q=0;q<4;q++) ((uint4*)trq)[i*4+q] = src[q];
  }
  #pragma unroll
  for(int r=0;r<64;r++) asm volatile("" : "+v"(trq[r]));

  float rsc = rscale[jstar];
  int Tb = Tl[b];
  const float LOGC = __logf(120.0f);
  __syncthreads();

  // ---- t = 0 ----
  int m = xls[0];
  float e  = bf2f((unsigned)emTu[(size_t)m*HN + jstar]);
  float nv = e * P[jstar];
  {
    float ws_ = wsum(nv), wm_ = wmax(nv);
    if(jh==0 && L==0){ red2[kr] = ws_; red2[8+kr] = wm_; }
  }
  __syncthreads();
  float S = 0.f, M = 0.f;
  #pragma unroll
  for(int r=0;r<8;r++) S += red2[r];
  #pragma unroll
  for(int r=0;r<8;r++) M = fmaxf(M, red2[8+r]);
  float lS = __logf(S);
  float c  = pric[0] + lS;
  float lg = __logf(M) - lS;
  // pack alpha u8 (wave-local)
  aqb[(w<<6) + L] = (unsigned char)__float2int_rn(nv * (120.0f/M));
  asm volatile("" ::: "memory");
  unsigned int apk[16];
  #pragma unroll
  for(int q=0;q<4;q++) ((uint4*)apk)[q] = ((const uint4*)(aqb + (w<<6)))[q];

  int mn = xls[(Tb>1)?1:0];
  float en = bf2f((unsigned)emTu[(size_t)mn*HN + jstar]);

  for(int tt=1; tt<Tb; tt++){
    e = en;
    int tn = (tt+1 < HT)? tt+1 : HT-1;
    mn = xls[tn];
    en = bf2f((unsigned)emTu[(size_t)mn*HN + jstar]);   // prefetch next step

    // ---- Phase A: 64 u8-dot4, all operands in registers ----
    int a0=0,a1=0,a2=0,a3=0;
    #pragma unroll
    for(int q=0;q<16;q++){
      a0 = dot4u8(trq[q],    apk[q], a0);
      a1 = dot4u8(trq[16+q], apk[q], a1);
      a2 = dot4u8(trq[32+q], apk[q], a2);
      a3 = dot4u8(trq[48+q], apk[q], a3);
    }
    int base = (w<<8) + L;     // (w*4+i)*64+L = w*256 + i*64 + L
    redi[base      ] = a0;
    redi[base +  64] = a1;
    redi[base + 128] = a2;
    redi[base + 192] = a3;
    __syncthreads();                       // B1

    // ---- finalize own state jstar: sum 8 k-slice partials ----
    int D = 0;
    #pragma unroll
    for(int k2=0;k2<8;k2++) D += redi[((k2*2 + jh2)*4 + ii)*64 + ll];
    nv = (float)D * rsc * e;
    {
      float ws_ = wsum(nv), wm_ = wmax(nv);
      if(jh==0 && L==0){ red2[kr] = ws_; red2[8+kr] = wm_; }
    }
    __syncthreads();                       // B2
    S = 0.f; M = 0.f;
    #pragma unroll
    for(int r=0;r<8;r++) S += red2[r];
    #pragma unroll
    for(int r=0;r<8;r++) M = fmaxf(M, red2[8+r]);
    lS = __logf(S);
    c += lS - LOGC + lg;
    lg = __logf(M) - lS;
    aqb[(w<<6) + L] = (unsigned char)__float2int_rn(nv * (120.0f/M));
    asm volatile("" ::: "memory");
    #pragma unroll
    for(int q=0;q<4;q++) ((uint4*)apk)[q] = ((const uint4*)(aqb + (w<<6)))[q];
  }
  if(t==0) out[b] = c;
}

extern "C" void kernel_launch(void* const* d_in, const int* in_sizes, int n_in,
                              void* d_out, int out_size, void* d_ws, size_t ws_size,
                              hipStream_t stream){
  const int*   x   = (const int*)d_in[0];
  const int*   T   = (const int*)d_in[1];
  const float* em  = (const float*)d_in[2];
  const float* tr  = (const float*)d_in[3];
  const float* pri = (const float*)d_in[4];
  float* out = (float*)d_out;

  char* ws = (char*)d_ws;
  float* em_lse = (float*)ws;                                   // 2 KiB
  float* P      = (float*)(ws + 2048);                          // 2 KiB
  float* pric   = (float*)(ws + 4096);                          // 16 B
  float* cmax   = (float*)(ws + 8192);                          // 2 KiB
  float* csum   = (float*)(ws + 10240);                         // 2 KiB
  float* rscale = (float*)(ws + 12288);                         // 2 KiB
  unsigned short* emT = (unsigned short*)(ws + 24576);          // 4 MiB
  unsigned char*  TQb = (unsigned char*)(ws + 24576 + (size_t)HM*HN*2);  // 256 KiB

  k_em_lse<<<HN, 512, 0, stream>>>(em, em_lse);
  k_pri   <<<1,  512, 0, stream>>>(pri, P, pric);
  k_trcol <<<HN, 512, 0, stream>>>(tr, cmax, csum);
  k_trrow <<<HN, 512, 0, stream>>>(tr, cmax, csum, TQb, rscale);
  k_em_tab<<<dim3(HM/64, HN/64), 256, 0, stream>>>(em, em_lse, emT);

  k_fwd<<<HB, 1024, 0, stream>>>(x, T, emT, P, pric, rscale, TQb, out);
}

// Round 9
// 944.882 us; speedup vs baseline: 1.4687x; 1.1340x over previous
//
#include <hip/hip_runtime.h>
#include <math.h>

#define HN 512   // hidden states
#define HM 4096  // emission symbols
#define HB 64    // batch
#define HT 512   // max seq len

__device__ __forceinline__ int dot4u8(unsigned int a, unsigned int b, int c){
#if __has_builtin(__builtin_amdgcn_sdot4)
  return __builtin_amdgcn_sdot4((int)a, (int)b, c, false);   // bytes <=127 -> sign-safe
#elif __has_builtin(__builtin_amdgcn_udot4)
  return (int)__builtin_amdgcn_udot4(a, b, (unsigned)c, false);
#else
  c += (int)(a & 0xffu)        * (int)(b & 0xffu);
  c += (int)((a>>8) & 0xffu)   * (int)((b>>8) & 0xffu);
  c += (int)((a>>16) & 0xffu)  * (int)((b>>16) & 0xffu);
  c += (int)(a>>24)            * (int)(b>>24);
  return c;
#endif
}

__device__ __forceinline__ float wsum(float v){
  #pragma unroll
  for(int o=32;o>0;o>>=1) v += __shfl_xor(v,o,64);
  return v;
}
__device__ __forceinline__ float wmax(float v){
  #pragma unroll
  for(int o=32;o>0;o>>=1) v = fmaxf(v,__shfl_xor(v,o,64));
  return v;
}

__device__ __forceinline__ float blockSum512(float v, float* red, float* bc){
  v = wsum(v);
  if((threadIdx.x & 63)==0) red[threadIdx.x>>6] = v;
  __syncthreads();
  if(threadIdx.x < 64){
    float s = (threadIdx.x<8)? red[threadIdx.x] : 0.0f;
    #pragma unroll
    for(int o=4;o>0;o>>=1) s += __shfl_xor(s,o,64);
    if(threadIdx.x==0) *bc = s;
  }
  __syncthreads();
  return *bc;
}
__device__ __forceinline__ float blockMax512(float v, float* red, float* bc){
  v = wmax(v);
  if((threadIdx.x & 63)==0) red[threadIdx.x>>6] = v;
  __syncthreads();
  if(threadIdx.x < 64){
    float s = (threadIdx.x<8)? red[threadIdx.x] : -INFINITY;
    #pragma unroll
    for(int o=4;o>0;o>>=1) s = fmaxf(s, __shfl_xor(s,o,64));
    if(threadIdx.x==0) *bc = s;
  }
  __syncthreads();
  return *bc;
}

__device__ __forceinline__ unsigned short f2bf(float f){
  unsigned int u = __float_as_uint(f);
  unsigned int r = (u + 0x7fffu + ((u>>16)&1u)) >> 16;  // RNE
  return (unsigned short)r;
}
__device__ __forceinline__ float bf2f(unsigned int w){ return __uint_as_float(w<<16); }

// ---------------- prep kernels ----------------

__global__ __launch_bounds__(512) void k_em_lse(const float* __restrict__ em, float* __restrict__ em_lse){
  __shared__ float red[8]; __shared__ float bc;
  int r = blockIdx.x;
  const float* row = em + (size_t)r*HM;
  float mx = -INFINITY;
  for(int i=threadIdx.x;i<HM;i+=512) mx = fmaxf(mx, row[i]);
  mx = blockMax512(mx, red, &bc);
  float s = 0.f;
  for(int i=threadIdx.x;i<HM;i+=512) s += expf(row[i]-mx);
  s = blockSum512(s, red, &bc);
  if(threadIdx.x==0) em_lse[r] = mx + logf(s);
}

__global__ __launch_bounds__(512) void k_pri(const float* __restrict__ pri, float* __restrict__ P, float* __restrict__ pric){
  __shared__ float red[8]; __shared__ float bc;
  int j = threadIdx.x;
  float v = pri[j];
  float mx = blockMax512(v, red, &bc);
  float w = expf(v-mx);
  float s = blockSum512(w, red, &bc);
  P[j] = w;
  if(j==0) *pric = -logf(s);
}

// emT[m][j] = bf16( exp(log_em[j][m]) ), LDS-tiled transpose
__global__ __launch_bounds__(256) void k_em_tab(const float* __restrict__ em, const float* __restrict__ em_lse,
                                                unsigned short* __restrict__ emT){
  __shared__ unsigned short tile[64][66];
  __shared__ float lsl[64];
  int m0 = blockIdx.x*64, j0 = blockIdx.y*64;
  int tx = threadIdx.x & 63, ty = threadIdx.x >> 6;
  if(threadIdx.x < 64) lsl[threadIdx.x] = em_lse[j0 + threadIdx.x];
  __syncthreads();
  #pragma unroll
  for(int r=0;r<16;r++){
    int jl = ty*16 + r;
    float v = em[(size_t)(j0+jl)*HM + m0 + tx];
    tile[jl][tx] = f2bf(expf(v - lsl[jl]));
  }
  __syncthreads();
  #pragma unroll
  for(int r=0;r<16;r++){
    int ml = ty*16 + r;
    emT[(size_t)(m0+ml)*HN + j0 + tx] = tile[tx][ml];
  }
}

// column stats of transition col-softmax: cmax[k], csum[k]
__global__ __launch_bounds__(512) void k_trcol(const float* __restrict__ tr,
                                               float* __restrict__ cmax, float* __restrict__ csum){
  __shared__ float red[8]; __shared__ float bc;
  int k = blockIdx.x, j = threadIdx.x;
  float v = tr[(size_t)j*HN + k];
  float mx = blockMax512(v, red, &bc);
  float s  = blockSum512(expf(v-mx), red, &bc);
  if(j==0){ cmax[k] = mx; csum[k] = s; }
}

// row pass: Tr[j,k] = exp(tr-cmax)/csum; rm_j = row max; TQb[j][k] = u8 round(Tr*127/rm);
// rscale[j] = rm_j/127 (descale folded)
__global__ __launch_bounds__(512) void k_trrow(const float* __restrict__ tr,
                                               const float* __restrict__ cmax, const float* __restrict__ csum,
                                               unsigned char* __restrict__ TQb, float* __restrict__ rscale){
  __shared__ float red[8]; __shared__ float bc;
  int j = blockIdx.x, k = threadIdx.x;
  float v = expf(tr[(size_t)j*HN + k] - cmax[k]) / csum[k];
  float rm = blockMax512(v, red, &bc);
  TQb[(size_t)j*HN + k] = (unsigned char)__float2int_rn(v * (127.0f/rm));
  if(k==0) rscale[j] = rm * (1.0f/127.0f);
}

// ---------------- forward recurrence ----------------
// 64 blocks (1/batch), 1024 threads = 16 waves. wave w: k-slice kw=w>>1, j-half jh=w&1.
// Writer role: thread (w,L) computes u8-dot4 partials for states jh*256+4L+i (i<4)
// over k in [kw*64, kw*64+64) with Tr held in trq[64] VGPRs.
// Reader role: finalizes jstar = kw*64 + pi(L), pi(L)=4(L&15)+(L>>4) — chosen with the
// XOR-swizzled redi layout so Phase-B reads are <=2-way bank aliased (free) instead of
// round-8's 4-way (1.08e7 conflicts).
// amdgpu_waves_per_eu(4,4): VGPR budget 512/4=128 >= live ~105 so trq stays resident
// (round 8: default budget ~64 -> trq spilled to scratch, 256 KB/block/step L1 stream).
// asm pins re-executed EVERY iteration make spilling trq cost a per-step reload in the
// allocator's model.
__global__ __launch_bounds__(1024) __attribute__((amdgpu_waves_per_eu(4, 4)))
void k_fwd(const int* __restrict__ x, const int* __restrict__ Tl,
           const unsigned short* __restrict__ emTu,
           const float* __restrict__ P, const float* __restrict__ pric,
           const float* __restrict__ rscale,
           const unsigned char* __restrict__ TQb,
           float* __restrict__ out){
  __shared__ int   xls[HT];
  __shared__ int   redi[4096];                 // w*256 + i*64 + (L^(8i))
  __shared__ float red2[16];                   // [kw]=sum, [8+kw]=max
  __shared__ __align__(16) unsigned char aqb[1024];  // wave-private alpha u8: w*64 + n

  const int t = threadIdx.x, w = t>>6, L = t&63, b = blockIdx.x;
  const int kw = w>>1, jh = w&1;
  const int pj = 4*(L&15) + (L>>4);            // pi(L)
  const int jstar = kw*64 + pj;                // state this thread finalizes
  const int i2 = L>>4;
  const int L2 = (kw&3)*16 + (L&15);
  const int jh2 = kw>>2;
  const int roff = jh2*256 + i2*64 + (L2 ^ (8*i2));   // reader base offset

  if(t < HT) xls[t] = x[b*HT + t];

  // stage register Tr tile: 4 rows x 64 k-bytes = 16 uint4
  unsigned int trq[64];
  #pragma unroll
  for(int i=0;i<4;i++){
    int j = jh*256 + 4*L + i;
    const uint4* src = (const uint4*)(TQb + (size_t)j*HN + kw*64);
    #pragma unroll
    for(int q=0;q<4;q++) ((uint4*)trq)[i*4+q] = src[q];
  }
  #pragma unroll
  for(int r=0;r<64;r++) asm volatile("" : "+v"(trq[r]));

  float rsc = rscale[jstar];
  int Tb = Tl[b];
  const float LOGC = __logf(120.0f);
  __syncthreads();

  // ---- t = 0 ----
  int m = xls[0];
  float e  = bf2f((unsigned)emTu[(size_t)m*HN + jstar]);
  float nv = e * P[jstar];
  {
    float ws_ = wsum(nv), wm_ = wmax(nv);
    if(jh==0 && L==0){ red2[kw] = ws_; red2[8+kw] = wm_; }
  }
  __syncthreads();
  float S = 0.f, M = 0.f;
  #pragma unroll
  for(int r=0;r<8;r++) S += red2[r];
  #pragma unroll
  for(int r=0;r<8;r++) M = fmaxf(M, red2[8+r]);
  float lS = __logf(S);
  float c  = pric[0] + lS;
  float lg = __logf(M) - lS;
  // pack alpha u8 (wave-local: aqb[w*64 + n] = alpha(kw*64+n))
  aqb[(w<<6) + pj] = (unsigned char)__float2int_rn(nv * (120.0f/M));
  asm volatile("" ::: "memory");
  unsigned int apk[16];
  #pragma unroll
  for(int q=0;q<4;q++) ((uint4*)apk)[q] = ((const uint4*)(aqb + (w<<6)))[q];

  int mn = xls[(Tb>1)?1:0];
  float en = bf2f((unsigned)emTu[(size_t)mn*HN + jstar]);

  for(int tt=1; tt<Tb; tt++){
    // re-pin every iteration: spilling trq would now cost a reload per step
    #pragma unroll
    for(int r=0;r<64;r++) asm volatile("" : "+v"(trq[r]));

    e = en;
    int tn = (tt+1 < HT)? tt+1 : HT-1;
    mn = xls[tn];
    en = bf2f((unsigned)emTu[(size_t)mn*HN + jstar]);   // prefetch next step

    // ---- Phase A: 64 u8-dot4, all operands in registers ----
    int a0=0,a1=0,a2=0,a3=0;
    #pragma unroll
    for(int q=0;q<16;q++){
      a0 = dot4u8(trq[q],    apk[q], a0);
      a1 = dot4u8(trq[16+q], apk[q], a1);
      a2 = dot4u8(trq[32+q], apk[q], a2);
      a3 = dot4u8(trq[48+q], apk[q], a3);
    }
    int basew = (w<<8);
    redi[basew       + (L ^  0)] = a0;       // i=0
    redi[basew +  64 + (L ^  8)] = a1;       // i=1
    redi[basew + 128 + (L ^ 16)] = a2;       // i=2
    redi[basew + 192 + (L ^ 24)] = a3;       // i=3
    __syncthreads();                       // B1

    // ---- finalize own state jstar: sum 8 k-slice partials (2-way max aliasing) ----
    int D = 0;
    #pragma unroll
    for(int k2=0;k2<8;k2++) D += redi[k2*512 + roff];
    nv = (float)D * rsc * e;
    {
      float ws_ = wsum(nv), wm_ = wmax(nv);
      if(jh==0 && L==0){ red2[kw] = ws_; red2[8+kw] = wm_; }
    }
    __syncthreads();                       // B2
    S = 0.f; M = 0.f;
    #pragma unroll
    for(int r=0;r<8;r++) S += red2[r];
    #pragma unroll
    for(int r=0;r<8;r++) M = fmaxf(M, red2[8+r]);
    lS = __logf(S);
    c += lS - LOGC + lg;
    lg = __logf(M) - lS;
    aqb[(w<<6) + pj] = (unsigned char)__float2int_rn(nv * (120.0f/M));
    asm volatile("" ::: "memory");
    #pragma unroll
    for(int q=0;q<4;q++) ((uint4*)apk)[q] = ((const uint4*)(aqb + (w<<6)))[q];
  }
  if(t==0) out[b] = c;
}

extern "C" void kernel_launch(void* const* d_in, const int* in_sizes, int n_in,
                              void* d_out, int out_size, void* d_ws, size_t ws_size,
                              hipStream_t stream){
  const int*   x   = (const int*)d_in[0];
  const int*   T   = (const int*)d_in[1];
  const float* em  = (const float*)d_in[2];
  const float* tr  = (const float*)d_in[3];
  const float* pri = (const float*)d_in[4];
  float* out = (float*)d_out;

  char* ws = (char*)d_ws;
  float* em_lse = (float*)ws;                                   // 2 KiB
  float* P      = (float*)(ws + 2048);                          // 2 KiB
  float* pric   = (float*)(ws + 4096);                          // 16 B
  float* cmax   = (float*)(ws + 8192);                          // 2 KiB
  float* csum   = (float*)(ws + 10240);                         // 2 KiB
  float* rscale = (float*)(ws + 12288);                         // 2 KiB
  unsigned short* emT = (unsigned short*)(ws + 24576);          // 4 MiB
  unsigned char*  TQb = (unsigned char*)(ws + 24576 + (size_t)HM*HN*2);  // 256 KiB

  k_em_lse<<<HN, 512, 0, stream>>>(em, em_lse);
  k_pri   <<<1,  512, 0, stream>>>(pri, P, pric);
  k_trcol <<<HN, 512, 0, stream>>>(tr, cmax, csum);
  k_trrow <<<HN, 512, 0, stream>>>(tr, cmax, csum, TQb, rscale);
  k_em_tab<<<dim3(HM/64, HN/64), 256, 0, stream>>>(em, em_lse, emT);

  k_fwd<<<HB, 1024, 0, stream>>>(x, T, emT, P, pric, rscale, TQb, out);
}